// Round 7
// baseline (577.089 us; speedup 1.0000x reference)
//
#include <hip/hip_runtime.h>

// QMixer — round 7: two-kernel split at 128-row tiles (halves L2 intensity).
// K1: gemm1 [128,512]x[512,640]^T (states->swizzled LDS, B 1-deep L2 prefetch)
//     + wf head + b1/v heads; h1 written to HBM bf16 with the XOR swizzle
//     BAKED INTO the layout (copy is swizzle-free by involution identity).
// K2: gemm2+mix: h1 tile [128][256] bf16 reg-staged to LDS (linear copy of the
//     pre-swizzled layout), B (w1_2) read DIRECT from L2, waves = 4 agent-
//     groups x 2 e-halves (B read once per block), 64 MFMA cover per 8-load
//     batch, ZERO barriers in the agent loop; 3-partial bf16 LDS reduce.

#define SDIM 512
#define HD   256
#define EDIM 64
#define NAG  32

typedef short short8v __attribute__((ext_vector_type(8)));
typedef short short4v __attribute__((ext_vector_type(4)));
typedef float f32x4  __attribute__((ext_vector_type(4)));

__device__ __forceinline__ unsigned short f2bf(float f) {
  unsigned int u = __float_as_uint(f);
  unsigned int r = (u + 0x7FFFu + ((u >> 16) & 1u)) >> 16;
  return (unsigned short)r;
}
__device__ __forceinline__ float bf2f(unsigned short u) {
  return __uint_as_float(((unsigned int)u) << 16);
}
__device__ __forceinline__ short4v cvt4(float4 a) {
  short4v r;
  r[0] = (short)f2bf(a.x); r[1] = (short)f2bf(a.y);
  r[2] = (short)f2bf(a.z); r[3] = (short)f2bf(a.w);
  return r;
}

// ---------------- convert weights to bf16 ----------------
// W0cat [640][512] = w1_0(256) | wf_0(256) | hb_w(64) | v0_w(64)
// w12b [2048][256]; wf2b [64][256]
__global__ void qmix_convert(const float* __restrict__ w1_0, const float* __restrict__ wf_0,
                             const float* __restrict__ hb_w, const float* __restrict__ v0_w,
                             const float* __restrict__ w1_2, const float* __restrict__ wf_2,
                             unsigned short* __restrict__ W0cat, unsigned short* __restrict__ w12b,
                             unsigned short* __restrict__ wf2b) {
  int i = blockIdx.x * 256 + threadIdx.x;
  if (i < 327680) {
    float v;
    if (i < 131072)      v = w1_0[i];
    else if (i < 262144) v = wf_0[i - 131072];
    else if (i < 294912) v = hb_w[i - 262144];
    else                 v = v0_w[i - 294912];
    W0cat[i] = f2bf(v);
  } else if (i < 851968) {
    w12b[i - 327680] = f2bf(w1_2[i - 327680]);
  } else if (i < 868352) {
    wf2b[i - 851968] = f2bf(wf_2[i - 851968]);
  }
}

// ---------------- K1: gemm1 + wf + heads, 128-row blocks ----------------
__global__ __launch_bounds__(512, 2) void qmix_k1(
    const float* __restrict__ states, const unsigned short* __restrict__ W0cat,
    const unsigned short* __restrict__ wf2b,
    const float* __restrict__ b1_0, const float* __restrict__ bf_0,
    const float* __restrict__ hb_b, const float* __restrict__ v0_b,
    const float* __restrict__ v2_w, const float* __restrict__ bf_2,
    unsigned short* __restrict__ h1g, unsigned short* __restrict__ b1h,
    unsigned short* __restrict__ wfinh, float* __restrict__ vbuf)
{
  __shared__ unsigned short sA[128 * 512];     // 128 KB: states, then h1|hf (swizzled)

  const int t    = threadIdx.x;
  const int r0   = blockIdx.x * 128;
  const int wave = t >> 6, lane = t & 63;
  const int lrow = lane & 15, lk = lane >> 4;

  // gemm1 B prefetch for ks=0,1 (L2-resident weights)
  const int colbase = wave * 80;
  const unsigned short* bp[5];
#pragma unroll
  for (int f = 0; f < 5; f++)
    bp[f] = W0cat + (size_t)(colbase + f * 16 + lrow) * SDIM + 8 * lk;
  short8v bregs[2][5];
#pragma unroll
  for (int f = 0; f < 5; f++) bregs[0][f] = *(const short8v*)(bp[f]);
#pragma unroll
  for (int f = 0; f < 5; f++) bregs[1][f] = *(const short8v*)(bp[f] + 32);

  // ---- stage states [128][512] f32 -> bf16 swizzled LDS (two reg batches) ----
  const float4* gS4 = (const float4*)(states + (size_t)r0 * SDIM);
  {
    float4 L[16];
#pragma unroll
    for (int h = 0; h < 2; h++) {
#pragma unroll
      for (int it = 0; it < 16; it++) L[it] = gS4[(h * 16 + it) * 512 + t];
#pragma unroll
      for (int it = 0; it < 16; it++) {
        int idx = (h * 16 + it) * 512 + t;
        int row = idx >> 7, c4 = idx & 127;
        int byte = row * 1024 + ((c4 * 8) ^ ((row & 7) << 4));
        *(short4v*)((char*)sA + byte) = cvt4(L[it]);
      }
    }
  }
  __syncthreads();   // bar1

  // ---- gemm1: acc[8][5], wave tile 128 rows x 80 cols ----
  f32x4 acc[8][5];
#pragma unroll
  for (int i = 0; i < 8; i++)
#pragma unroll
    for (int f = 0; f < 5; f++) acc[i][f] = (f32x4){0.f, 0.f, 0.f, 0.f};

#pragma unroll 1
  for (int ks = 0; ks < 16; ks++) {
    const int p = ks & 1;
#pragma unroll
    for (int i = 0; i < 8; i++) {
      int row = i * 16 + lrow;
      int byte = row * 1024 + ((ks * 64 + lk * 16) ^ ((row & 7) << 4));
      short8v af = *(const short8v*)((const char*)sA + byte);
#pragma unroll
      for (int f = 0; f < 5; f++)
        acc[i][f] = __builtin_amdgcn_mfma_f32_16x16x32_bf16(af, bregs[p][f], acc[i][f], 0, 0, 0);
    }
    if (ks < 14) {
#pragma unroll
      for (int f = 0; f < 5; f++) bregs[p][f] = *(const short8v*)(bp[f] + (ks + 2) * 32);
    }
  }

  __syncthreads();   // bar2: all sA reads done; safe to overwrite with h-tile

  // ---- epilogue: heads by column range ----
  {
    float vs[8][4];
#pragma unroll
    for (int i = 0; i < 8; i++)
#pragma unroll
      for (int rr = 0; rr < 4; rr++) vs[i][rr] = 0.f;

#pragma unroll
    for (int f = 0; f < 5; f++) {
      int cb  = colbase + f * 16;    // wave-uniform
      int col = cb + lrow;
      if (cb < 512) {
        float bv = (cb < 256) ? b1_0[col] : bf_0[col - 256];
#pragma unroll
        for (int i = 0; i < 8; i++)
#pragma unroll
          for (int rr = 0; rr < 4; rr++) {
            int row = i * 16 + lk * 4 + rr;
            float v = fmaxf(acc[i][f][rr] + bv, 0.f);
            int byte = row * 1024 + ((col * 2) ^ ((row & 7) << 4));
            *(unsigned short*)((char*)sA + byte) = f2bf(v);
          }
      } else if (cb < 576) {
        int e = col - 512;
        float bv = hb_b[e];
#pragma unroll
        for (int i = 0; i < 8; i++)
#pragma unroll
          for (int rr = 0; rr < 4; rr++) {
            int row = i * 16 + lk * 4 + rr;
            b1h[(size_t)(r0 + row) * EDIM + e] = f2bf(acc[i][f][rr] + bv);
          }
      } else {
        int e = col - 576;
        float bv = v0_b[e], wv = v2_w[e];
#pragma unroll
        for (int i = 0; i < 8; i++)
#pragma unroll
          for (int rr = 0; rr < 4; rr++)
            vs[i][rr] = fmaf(fmaxf(acc[i][f][rr] + bv, 0.f), wv, vs[i][rr]);
      }
    }
    if (colbase == 560) {    // wave 7 owns the v head
#pragma unroll
      for (int i = 0; i < 8; i++)
#pragma unroll
        for (int rr = 0; rr < 4; rr++) {
          float v = vs[i][rr];
#pragma unroll
          for (int m = 1; m < 16; m <<= 1) v += __shfl_xor(v, m, 64);
          if (lrow == 0) vbuf[r0 + i * 16 + lk * 4 + rr] = v;
        }
    }
  }
  __syncthreads();   // bar3: h-tile complete

  // ---- wf: |hf @ wf_2^T + bf_2| -> wfinh bf16 ----
  {
    const int wr2 = wave >> 1;     // 0..3 (16-row groups... rows 128 -> 2 frags each)
    const int wc2 = wave & 1;      // e-half
    f32x4 wfa[2][2];
#pragma unroll
    for (int i2 = 0; i2 < 2; i2++)
#pragma unroll
      for (int j = 0; j < 2; j++) wfa[i2][j] = (f32x4){0.f, 0.f, 0.f, 0.f};
#pragma unroll
    for (int kf = 0; kf < 8; kf++) {
      short8v bf2v[2];
#pragma unroll
      for (int j = 0; j < 2; j++)
        bf2v[j] = *(const short8v*)(wf2b + (size_t)(wc2 * 32 + j * 16 + lrow) * HD + kf * 32 + 8 * lk);
#pragma unroll
      for (int i2 = 0; i2 < 2; i2++) {
        int row = wr2 * 32 + i2 * 16 + lrow;
        int byte = row * 1024 + 512 + ((kf * 64 + lk * 16) ^ ((row & 7) << 4));
        short8v af2 = *(const short8v*)((const char*)sA + byte);
#pragma unroll
        for (int j = 0; j < 2; j++)
          wfa[i2][j] = __builtin_amdgcn_mfma_f32_16x16x32_bf16(af2, bf2v[j], wfa[i2][j], 0, 0, 0);
      }
    }
#pragma unroll
    for (int i2 = 0; i2 < 2; i2++)
#pragma unroll
      for (int j = 0; j < 2; j++) {
        int e = wc2 * 32 + j * 16 + lrow;
#pragma unroll
        for (int r = 0; r < 4; r++) {
          int row = wr2 * 32 + i2 * 16 + lk * 4 + r;
          wfinh[(size_t)(r0 + row) * EDIM + e] = f2bf(fabsf(wfa[i2][j][r] + bf_2[e]));
        }
      }
  }

  // ---- h1 repack to HBM (swizzle baked in; copy is identity on positions) ----
  {
    char* dst = (char*)h1g + (size_t)r0 * 512;
#pragma unroll
    for (int u = 0; u < 8; u++) {
      int idx = u * 512 + t;          // 4096 chunks of 16B
      int row = idx >> 5;
      int p   = (idx & 31) * 16;
      short8v v = *(const short8v*)((const char*)sA + row * 1024 + p);
      *(short8v*)(dst + row * 512 + p) = v;
    }
  }
}

// ---------------- K2: gemm2 + mix, 128-row blocks, barrier-free agent loop ----------------
__global__ __launch_bounds__(512, 2) void qmix_k2(
    const unsigned short* __restrict__ h1g, const unsigned short* __restrict__ w12b,
    const float* __restrict__ agent_qs, const float* __restrict__ b1_2,
    const unsigned short* __restrict__ b1h, const unsigned short* __restrict__ wfinh,
    const float* __restrict__ vbuf, const float* __restrict__ v2_b,
    float* __restrict__ out)
{
  __shared__ unsigned char h1s[128 * 512];         // 64 KB (pre-swizzled layout)
  __shared__ float q_lds[128 * 33];                // 16.9 KB
  __shared__ unsigned short pbuf[3][128][EDIM];    // 48 KB bf16 partials
  __shared__ float ypart[2][128];                  // 1 KB

  const int t    = threadIdx.x;
  const int r0   = blockIdx.x * 128;
  const int wave = t >> 6, lane = t & 63;
  const int lrow = lane & 15, lk = lane >> 4;
  const int g  = wave >> 1;   // agent-group 0..3 (8 agents each)
  const int wc = wave & 1;    // e-half

  // ---- stage h1 tile (reg-staged linear copy) + q tile ----
  {
    const char* src = (const char*)h1g + (size_t)r0 * 512;
    short8v L[8];
#pragma unroll
    for (int it = 0; it < 8; it++)
      L[it] = *(const short8v*)(src + (it * 512 + t) * 16);
#pragma unroll
    for (int it = 0; it < 8; it++)
      *(short8v*)(h1s + (it * 512 + t) * 16) = L[it];

    const float4* gq = (const float4*)(agent_qs + (size_t)r0 * NAG);
#pragma unroll
    for (int v = 0; v < 2; v++) {
      int idx = v * 512 + t;
      float4 qv = gq[idx];
      int row = idx >> 3, c = (idx & 7) * 4;
      q_lds[row * 33 + c + 0] = qv.x;
      q_lds[row * 33 + c + 1] = qv.y;
      q_lds[row * 33 + c + 2] = qv.z;
      q_lds[row * 33 + c + 3] = qv.w;
    }
  }

  // prefetch first B batch (agent g*8, j=0) before the barrier
  short8v bdA[8], bdB[8];
  {
    const unsigned short* p = w12b + (size_t)((g * 8) * EDIM + wc * 32 + lrow) * HD + 8 * lk;
#pragma unroll
    for (int kf = 0; kf < 8; kf++) bdA[kf] = *(const short8v*)(p + kf * 32);
  }
  __syncthreads();   // bar1

  f32x4 hac[8][2];
#pragma unroll
  for (int i = 0; i < 8; i++) {
    hac[i][0] = (f32x4){0.f, 0.f, 0.f, 0.f};
    hac[i][1] = (f32x4){0.f, 0.f, 0.f, 0.f};
  }

#pragma unroll 1
  for (int s = 0; s < 8; s++) {
    const int a = g * 8 + s;
    // prefetch (a, j=1)
    {
      const unsigned short* p = w12b + (size_t)(a * EDIM + wc * 32 + 16 + lrow) * HD + 8 * lk;
#pragma unroll
      for (int kf = 0; kf < 8; kf++) bdB[kf] = *(const short8v*)(p + kf * 32);
    }
    // compute j=0 from bdA: 8 row-frags x 8 kf
    {
      float bb = b1_2[a * EDIM + wc * 32 + lrow];
#pragma unroll
      for (int i = 0; i < 8; i++) {
        int row = i * 16 + lrow;
        int rb  = row * 512, sw = (row & 7) << 4;
        f32x4 T = (f32x4){0.f, 0.f, 0.f, 0.f};
#pragma unroll
        for (int kf = 0; kf < 8; kf++) {
          short8v af = *(const short8v*)(h1s + rb + ((kf * 64 + lk * 16) ^ sw));
          T = __builtin_amdgcn_mfma_f32_16x16x32_bf16(af, bdA[kf], T, 0, 0, 0);
        }
#pragma unroll
        for (int r = 0; r < 4; r++) {
          float qv = q_lds[(i * 16 + lk * 4 + r) * 33 + a];
          hac[i][0][r] = fmaf(qv, fabsf(T[r] + bb), hac[i][0][r]);
        }
      }
    }
    // prefetch (a+1, j=0)
    if (s < 7) {
      const unsigned short* p = w12b + (size_t)((a + 1) * EDIM + wc * 32 + lrow) * HD + 8 * lk;
#pragma unroll
      for (int kf = 0; kf < 8; kf++) bdA[kf] = *(const short8v*)(p + kf * 32);
    }
    // compute j=1 from bdB
    {
      float bb = b1_2[a * EDIM + wc * 32 + 16 + lrow];
#pragma unroll
      for (int i = 0; i < 8; i++) {
        int row = i * 16 + lrow;
        int rb  = row * 512, sw = (row & 7) << 4;
        f32x4 T = (f32x4){0.f, 0.f, 0.f, 0.f};
#pragma unroll
        for (int kf = 0; kf < 8; kf++) {
          short8v af = *(const short8v*)(h1s + rb + ((kf * 64 + lk * 16) ^ sw));
          T = __builtin_amdgcn_mfma_f32_16x16x32_bf16(af, bdB[kf], T, 0, 0, 0);
        }
#pragma unroll
        for (int r = 0; r < 4; r++) {
          float qv = q_lds[(i * 16 + lk * 4 + r) * 33 + a];
          hac[i][1][r] = fmaf(qv, fabsf(T[r] + bb), hac[i][1][r]);
        }
      }
    }
  }

  // ---- groups 1..3 write partials (bf16) ----
  if (g >= 1) {
#pragma unroll
    for (int i = 0; i < 8; i++)
#pragma unroll
      for (int j = 0; j < 2; j++)
#pragma unroll
        for (int r = 0; r < 4; r++) {
          int row = i * 16 + lk * 4 + r;
          int e   = wc * 32 + j * 16 + lrow;
          pbuf[g - 1][row][e] = f2bf(hac[i][j][r]);
        }
  }
  __syncthreads();   // bar2

  // ---- group 0 waves: combine, elu, multiply wfin, row-reduce ----
  if (g == 0) {
    float yv[8][4];
#pragma unroll
    for (int i = 0; i < 8; i++)
#pragma unroll
      for (int r = 0; r < 4; r++) yv[i][r] = 0.f;
#pragma unroll
    for (int i = 0; i < 8; i++) {
#pragma unroll
      for (int j = 0; j < 2; j++) {
        int e = wc * 32 + j * 16 + lrow;
#pragma unroll
        for (int r = 0; r < 4; r++) {
          int row = i * 16 + lk * 4 + r;
          float hid = hac[i][j][r]
                    + bf2f(pbuf[0][row][e]) + bf2f(pbuf[1][row][e]) + bf2f(pbuf[2][row][e]);
          float pre = hid + bf2f(b1h[(size_t)(r0 + row) * EDIM + e]);
          float h = pre > 0.f ? pre : expm1f(pre);
          float wf = bf2f(wfinh[(size_t)(r0 + row) * EDIM + e]);
          yv[i][r] = fmaf(h, wf, yv[i][r]);
        }
      }
    }
#pragma unroll
    for (int m = 1; m < 16; m <<= 1)
#pragma unroll
      for (int i = 0; i < 8; i++)
#pragma unroll
        for (int r = 0; r < 4; r++) yv[i][r] += __shfl_xor(yv[i][r], m, 64);
    if (lrow == 0) {
#pragma unroll
      for (int i = 0; i < 8; i++)
#pragma unroll
        for (int r = 0; r < 4; r++)
          ypart[wc][i * 16 + lk * 4 + r] = yv[i][r];
    }
  }
  __syncthreads();   // bar3
  if (t < 128) {
    out[r0 + t] = ypart[0][t] + ypart[1][t] + vbuf[r0 + t] + v2_b[0];
  }
}

extern "C" void kernel_launch(void* const* d_in, const int* in_sizes, int n_in,
                              void* d_out, int out_size, void* d_ws, size_t ws_size,
                              hipStream_t stream) {
  const float* agent_qs = (const float*)d_in[0];
  const float* states   = (const float*)d_in[1];
  const float* w1_0 = (const float*)d_in[2];
  const float* b1_0 = (const float*)d_in[3];
  const float* w1_2 = (const float*)d_in[4];
  const float* b1_2 = (const float*)d_in[5];
  const float* wf_0 = (const float*)d_in[6];
  const float* bf_0 = (const float*)d_in[7];
  const float* wf_2 = (const float*)d_in[8];
  const float* bf_2 = (const float*)d_in[9];
  const float* hb_w = (const float*)d_in[10];
  const float* hb_b = (const float*)d_in[11];
  const float* v0_w = (const float*)d_in[12];
  const float* v0_b = (const float*)d_in[13];
  const float* v2_w = (const float*)d_in[14];
  const float* v2_b = (const float*)d_in[15];

  char* ws = (char*)d_ws;
  unsigned short* W0cat = (unsigned short*)ws;                  //    655,360 B
  unsigned short* w12b  = (unsigned short*)(ws + 655360);       //  1,048,576 B
  unsigned short* wf2b  = (unsigned short*)(ws + 1703936);      //     32,768 B
  unsigned short* h1g   = (unsigned short*)(ws + 1736704);      // 16,777,216 B
  unsigned short* b1h   = (unsigned short*)(ws + 18513920);     //  4,194,304 B
  unsigned short* wfinh = (unsigned short*)(ws + 22708224);     //  4,194,304 B
  float*          vbuf  = (float*)(ws + 26902528);              //    131,072 B

  qmix_convert<<<3392, 256, 0, stream>>>(w1_0, wf_0, hb_w, v0_w, w1_2, wf_2,
                                         W0cat, w12b, wf2b);
  qmix_k1<<<256, 512, 0, stream>>>(states, W0cat, wf2b, b1_0, bf_0, hb_b, v0_b,
                                   v2_w, bf_2, h1g, b1h, wfinh, vbuf);
  qmix_k2<<<256, 512, 0, stream>>>(h1g, w12b, agent_qs, b1_2, b1h, wfinh, vbuf,
                                   v2_b, (float*)d_out);
}

// Round 8
// 184.984 us; speedup vs baseline: 3.1197x; 3.1197x over previous
//
#include <hip/hip_runtime.h>

// QMixer — round 8: round-6 chassis + register-budget fix.
//   - __launch_bounds__(512,1): LDS caps at 1 block/CU anyway; VGPR cap 128->256
//     (rounds 6/7 regressed because the 128-cap spilled/serialized the gemm2
//      prefetch pipeline -> 581 MB scratch traffic in r7).
//   - gemm2: direct-L2 B reads, ring-4 static prefetch (depth 2), hac split
//     into hac0/hac1 (static j), zero barriers in the agent loop.
// Everything else identical to the replay-proven round-6 kernel.

#define SDIM 512
#define HD   256
#define EDIM 64
#define NAG  32

typedef short short8v __attribute__((ext_vector_type(8)));
typedef short short4v __attribute__((ext_vector_type(4)));
typedef float f32x4  __attribute__((ext_vector_type(4)));

__device__ __forceinline__ unsigned short f2bf(float f) {
  unsigned int u = __float_as_uint(f);
  unsigned int r = (u + 0x7FFFu + ((u >> 16) & 1u)) >> 16;
  return (unsigned short)r;
}

__device__ __forceinline__ short4v cvt4(float4 a) {
  short4v r;
  r[0] = (short)f2bf(a.x); r[1] = (short)f2bf(a.y);
  r[2] = (short)f2bf(a.z); r[3] = (short)f2bf(a.w);
  return r;
}

// ---------------- convert weights to bf16 ----------------
// W0cat [640][512] = w1_0(256) | wf_0(256) | hb_w(64) | v0_w(64)
// w12b [2048][256]; wf2b [64][256]
__global__ void qmix_convert(const float* __restrict__ w1_0, const float* __restrict__ wf_0,
                             const float* __restrict__ hb_w, const float* __restrict__ v0_w,
                             const float* __restrict__ w1_2, const float* __restrict__ wf_2,
                             unsigned short* __restrict__ W0cat, unsigned short* __restrict__ w12b,
                             unsigned short* __restrict__ wf2b) {
  int i = blockIdx.x * 256 + threadIdx.x;
  if (i < 327680) {
    float v;
    if (i < 131072)      v = w1_0[i];
    else if (i < 262144) v = wf_0[i - 131072];
    else if (i < 294912) v = hb_w[i - 262144];
    else                 v = v0_w[i - 294912];
    W0cat[i] = f2bf(v);
  } else if (i < 851968) {
    w12b[i - 327680] = f2bf(w1_2[i - 327680]);
  } else if (i < 868352) {
    wf2b[i - 851968] = f2bf(wf_2[i - 851968]);
  }
}

// ---------------- fused main kernel ----------------
__global__ __launch_bounds__(512, 1) void qmix_main(
    const float* __restrict__ agent_qs, const float* __restrict__ states,
    const unsigned short* __restrict__ W0cat, const unsigned short* __restrict__ w12b,
    const unsigned short* __restrict__ wf2b,
    const float* __restrict__ b1_0, const float* __restrict__ bf_0,
    const float* __restrict__ hb_b, const float* __restrict__ v0_b,
    const float* __restrict__ v2_w, const float* __restrict__ b1_2,
    const float* __restrict__ bf_2, const float* __restrict__ v2_b,
    float* __restrict__ out)
{
  __shared__ unsigned short sA[64 * 512];      // 64 KB: states, then h1|hf (swizzled)
  __shared__ float pbuf[2][64 * 65];           // 33.3 KB: gemm2 agent-half partials
  __shared__ float b1t[64 * 65];               // 16.6 KB
  __shared__ float q_lds[64 * 33];             // 8.4 KB
  __shared__ float vrow[64];
  __shared__ float ypart[4][64];               // 1 KB

  const int t    = threadIdx.x;
  const int r0   = blockIdx.x * 64;
  const int wave = t >> 6, lane = t & 63;
  const int lrow = lane & 15, lk = lane >> 4;

  // ---- phase 0: issue ALL global loads up front ----
  const float4* gS4 = (const float4*)(states + (size_t)r0 * SDIM);
  float4 L[16];
#pragma unroll
  for (int it = 0; it < 16; it++) L[it] = gS4[it * 512 + t];
  float4 qreg = ((const float4*)(agent_qs + (size_t)r0 * NAG))[t];

  // gemm1 B prefetch for ks=0,1 (L2-resident weights)
  const int colbase = wave * 80;
  const unsigned short* bp[5];
#pragma unroll
  for (int f = 0; f < 5; f++)
    bp[f] = W0cat + (size_t)(colbase + f * 16 + lrow) * SDIM + 8 * lk;
  short8v bregs[2][5];
#pragma unroll
  for (int f = 0; f < 5; f++) bregs[0][f] = *(const short8v*)(bp[f]);
#pragma unroll
  for (int f = 0; f < 5; f++) bregs[1][f] = *(const short8v*)(bp[f] + 32);

  // write FULL states tile + q tile, then one barrier
#pragma unroll
  for (int it = 0; it < 16; it++) {
    int idx = it * 512 + t;
    int row = idx >> 7, c4 = idx & 127;
    int byte = (row * 1024 + c4 * 8) ^ ((row & 7) << 4);
    *(short4v*)((char*)sA + byte) = cvt4(L[it]);
  }
  {
    int qrow = t >> 3, qc = (t & 7) * 4;
    q_lds[qrow * 33 + qc + 0] = qreg.x;
    q_lds[qrow * 33 + qc + 1] = qreg.y;
    q_lds[qrow * 33 + qc + 2] = qreg.z;
    q_lds[qrow * 33 + qc + 3] = qreg.w;
  }
  __syncthreads();   // bar1

  // ---- gemm1: acc[4][5], wave tile 64 rows x 80 cols ----
  f32x4 acc[4][5];
#pragma unroll
  for (int i = 0; i < 4; i++)
#pragma unroll
    for (int f = 0; f < 5; f++) acc[i][f] = (f32x4){0.f, 0.f, 0.f, 0.f};

#pragma unroll
  for (int ks = 0; ks < 16; ks++) {
    const int p = ks & 1;
    short8v af[4];
#pragma unroll
    for (int i = 0; i < 4; i++) {
      int row = i * 16 + lrow;
      int byte = (row * 1024 + ks * 64 + lk * 16) ^ ((row & 7) << 4);
      af[i] = *(const short8v*)((const char*)sA + byte);
    }
#pragma unroll
    for (int f = 0; f < 5; f++)
#pragma unroll
      for (int i = 0; i < 4; i++)
        acc[i][f] = __builtin_amdgcn_mfma_f32_16x16x32_bf16(af[i], bregs[p][f], acc[i][f], 0, 0, 0);
    if (ks < 14) {
#pragma unroll
      for (int f = 0; f < 5; f++) bregs[p][f] = *(const short8v*)(bp[f] + (ks + 2) * 32);
    }
  }

  __syncthreads();   // bar2: all sA reads done; safe to overwrite with h-tile

  // ---- gemm1 epilogue: heads by column range, h written back into sA ----
  {
    float vs[4][4];
#pragma unroll
    for (int i = 0; i < 4; i++)
#pragma unroll
      for (int rr = 0; rr < 4; rr++) vs[i][rr] = 0.f;

#pragma unroll
    for (int f = 0; f < 5; f++) {
      int cb  = colbase + f * 16;    // wave-uniform
      int col = cb + lrow;
      if (cb < 512) {
        float bv = (cb < 256) ? b1_0[col] : bf_0[col - 256];
#pragma unroll
        for (int i = 0; i < 4; i++)
#pragma unroll
          for (int rr = 0; rr < 4; rr++) {
            int row = i * 16 + lk * 4 + rr;
            float v = fmaxf(acc[i][f][rr] + bv, 0.f);
            int byte = (row * 1024 + col * 2) ^ ((row & 7) << 4);
            *(unsigned short*)((char*)sA + byte) = f2bf(v);
          }
      } else if (cb < 576) {
        int e = col - 512;
        float bv = hb_b[e];
#pragma unroll
        for (int i = 0; i < 4; i++)
#pragma unroll
          for (int rr = 0; rr < 4; rr++) {
            int row = i * 16 + lk * 4 + rr;
            b1t[row * 65 + e] = acc[i][f][rr] + bv;
          }
      } else {
        int e = col - 576;
        float bv = v0_b[e], wv = v2_w[e];
#pragma unroll
        for (int i = 0; i < 4; i++)
#pragma unroll
          for (int rr = 0; rr < 4; rr++)
            vs[i][rr] = fmaf(fmaxf(acc[i][f][rr] + bv, 0.f), wv, vs[i][rr]);
      }
    }
    if (colbase == 560) {    // wave 7 owns the v head
#pragma unroll
      for (int i = 0; i < 4; i++)
#pragma unroll
        for (int rr = 0; rr < 4; rr++) {
          float v = vs[i][rr];
#pragma unroll
          for (int m = 1; m < 16; m <<= 1) v += __shfl_xor(v, m, 64);
          if (lrow == 0) vrow[i * 16 + lk * 4 + rr] = v;
        }
    }
  }

  // ---- gemm2 wave roles ----
  const int wr = wave >> 2;        // 0..1 rows-half
  const int g  = (wave >> 1) & 1;  // 0..1 agents-half
  const int wc = wave & 1;         // 0..1 e-half

  // ring-4 prefetch buffers; batch b (0..31): agent a = g*16 + (b>>1), j = b&1
  short8v bq0[8], bq1[8], bq2[8], bq3[8];

  auto issueB = [&](int b, short8v (&dst)[8]) {
    if (b < 32) {
      int a    = g * 16 + (b >> 1);
      int ecol = wc * 32 + (b & 1) * 16 + lrow;
      const unsigned short* p = w12b + (size_t)(a * EDIM + ecol) * HD + 8 * lk;
#pragma unroll
      for (int kf = 0; kf < 8; kf++) dst[kf] = *(const short8v*)(p + kf * 32);
    }
  };

  // prologue: issue batches 0,1 before the barrier (latency hidden)
  issueB(0, bq0);
  issueB(1, bq1);

  __syncthreads();   // bar3: h-tile, b1t, vrow visible

  // hoist A fragments (h1, rows-half wr, K=256) into registers
  short8v afr[2][8];
#pragma unroll
  for (int i = 0; i < 2; i++) {
    int row = wr * 32 + i * 16 + lrow;
#pragma unroll
    for (int kf = 0; kf < 8; kf++) {
      int byte = (row * 1024 + kf * 64 + lk * 16) ^ ((row & 7) << 4);
      afr[i][kf] = *(const short8v*)((const char*)sA + byte);
    }
  }

  f32x4 hac0[2], hac1[2];   // [row-frag i], j=0 / j=1
  hac0[0] = (f32x4){0.f, 0.f, 0.f, 0.f};
  hac0[1] = (f32x4){0.f, 0.f, 0.f, 0.f};
  hac1[0] = (f32x4){0.f, 0.f, 0.f, 0.f};
  hac1[1] = (f32x4){0.f, 0.f, 0.f, 0.f};

  auto computeB = [&](int b, short8v (&buf)[8], f32x4 (&hj)[2]) {
    int a = g * 16 + (b >> 1);
    f32x4 T0 = (f32x4){0.f, 0.f, 0.f, 0.f};
    f32x4 T1 = (f32x4){0.f, 0.f, 0.f, 0.f};
#pragma unroll
    for (int kf = 0; kf < 8; kf++) {
      T0 = __builtin_amdgcn_mfma_f32_16x16x32_bf16(afr[0][kf], buf[kf], T0, 0, 0, 0);
      T1 = __builtin_amdgcn_mfma_f32_16x16x32_bf16(afr[1][kf], buf[kf], T1, 0, 0, 0);
    }
    float bb = b1_2[a * EDIM + wc * 32 + (b & 1) * 16 + lrow];
#pragma unroll
    for (int r = 0; r < 4; r++) {
      float qv0 = q_lds[(wr * 32 + lk * 4 + r) * 33 + a];
      float qv1 = q_lds[(wr * 32 + 16 + lk * 4 + r) * 33 + a];
      hj[0][r] = fmaf(qv0, fabsf(T0[r] + bb), hj[0][r]);
      hj[1][r] = fmaf(qv1, fabsf(T1[r] + bb), hj[1][r]);
    }
  };

#pragma unroll 1
  for (int b = 0; b < 32; b += 4) {
    issueB(b + 2, bq2);
    computeB(b + 0, bq0, hac0);
    issueB(b + 3, bq3);
    computeB(b + 1, bq1, hac1);
    issueB(b + 4, bq0);
    computeB(b + 2, bq2, hac0);
    issueB(b + 5, bq1);
    computeB(b + 3, bq3, hac1);
  }

  // ---- write agent-half partials ----
#pragma unroll
  for (int i = 0; i < 2; i++)
#pragma unroll
    for (int r = 0; r < 4; r++) {
      int row = wr * 32 + i * 16 + lk * 4 + r;
      pbuf[g][row * 65 + (wc * 32 + lrow)]      = hac0[i][r];
      pbuf[g][row * 65 + (wc * 32 + 16 + lrow)] = hac1[i][r];
    }

  // ---- wf B loads (global, issued before the barrier) ----
  const int eq = wave & 3;         // epilogue e-quarter
  short8v bwf[8];
#pragma unroll
  for (int kf = 0; kf < 8; kf++)
    bwf[kf] = *(const short8v*)(wf2b + (size_t)(eq * 16 + lrow) * HD + kf * 32 + 8 * lk);

  __syncthreads();   // bar4: pbuf visible

  // ---- wf: |hf @ wf_2^T + bf_2| for (rows-half wr, e-quarter eq) ----
  f32x4 wfa[2];
  wfa[0] = (f32x4){0.f, 0.f, 0.f, 0.f};
  wfa[1] = (f32x4){0.f, 0.f, 0.f, 0.f};
#pragma unroll
  for (int i = 0; i < 2; i++) {
    int row = wr * 32 + i * 16 + lrow;
#pragma unroll
    for (int kf = 0; kf < 8; kf++) {
      int byte = (row * 1024 + 512 + kf * 64 + lk * 16) ^ ((row & 7) << 4);
      short8v af2 = *(const short8v*)((const char*)sA + byte);
      wfa[i] = __builtin_amdgcn_mfma_f32_16x16x32_bf16(af2, bwf[kf], wfa[i], 0, 0, 0);
    }
  }

  // ---- final epilogue: elu(hid+b1)*wfin, reduce over e-quarter ----
  {
    float ys[2][4];
#pragma unroll
    for (int i = 0; i < 2; i++)
#pragma unroll
      for (int r = 0; r < 4; r++) {
        int row = wr * 32 + i * 16 + lk * 4 + r;
        int e   = eq * 16 + lrow;
        float hid = pbuf[0][row * 65 + e] + pbuf[1][row * 65 + e];
        float pre = hid + b1t[row * 65 + e];
        float h = pre > 0.f ? pre : expm1f(pre);
        float wfv = fabsf(wfa[i][r] + bf_2[e]);
        ys[i][r] = h * wfv;
      }
#pragma unroll
    for (int m = 1; m < 16; m <<= 1)
#pragma unroll
      for (int i = 0; i < 2; i++)
#pragma unroll
        for (int r = 0; r < 4; r++) ys[i][r] += __shfl_xor(ys[i][r], m, 64);
    if (lrow == 0) {
#pragma unroll
      for (int i = 0; i < 2; i++)
#pragma unroll
        for (int r = 0; r < 4; r++)
          ypart[eq][wr * 32 + i * 16 + lk * 4 + r] = ys[i][r];
    }
  }
  __syncthreads();   // bar5
  if (t < 64) {
    out[r0 + t] = ypart[0][t] + ypart[1][t] + ypart[2][t] + ypart[3][t]
                + vrow[t] + v2_b[0];
  }
}

extern "C" void kernel_launch(void* const* d_in, const int* in_sizes, int n_in,
                              void* d_out, int out_size, void* d_ws, size_t ws_size,
                              hipStream_t stream) {
  const float* agent_qs = (const float*)d_in[0];
  const float* states   = (const float*)d_in[1];
  const float* w1_0 = (const float*)d_in[2];
  const float* b1_0 = (const float*)d_in[3];
  const float* w1_2 = (const float*)d_in[4];
  const float* b1_2 = (const float*)d_in[5];
  const float* wf_0 = (const float*)d_in[6];
  const float* bf_0 = (const float*)d_in[7];
  const float* wf_2 = (const float*)d_in[8];
  const float* bf_2 = (const float*)d_in[9];
  const float* hb_w = (const float*)d_in[10];
  const float* hb_b = (const float*)d_in[11];
  const float* v0_w = (const float*)d_in[12];
  const float* v0_b = (const float*)d_in[13];
  const float* v2_w = (const float*)d_in[14];
  const float* v2_b = (const float*)d_in[15];

  char* ws = (char*)d_ws;
  unsigned short* W0cat = (unsigned short*)ws;                 //   655,360 B
  unsigned short* w12b  = (unsigned short*)(ws + 655360);      // 1,048,576 B
  unsigned short* wf2b  = (unsigned short*)(ws + 1703936);     //    32,768 B

  qmix_convert<<<3392, 256, 0, stream>>>(w1_0, wf_0, hb_w, v0_w, w1_2, wf_2,
                                         W0cat, w12b, wf2b);
  qmix_main<<<512, 512, 0, stream>>>(agent_qs, states, W0cat, w12b, wf2b,
                                     b1_0, bf_0, hb_b, v0_b, v2_w, b1_2, bf_2, v2_b,
                                     (float*)d_out);
}

// Round 9
// 126.288 us; speedup vs baseline: 4.5696x; 1.4648x over previous
//
#include <hip/hip_runtime.h>

// QMixer — round 9: r7's proven K1 + LDS-bandwidth-fixed K2.
// Model (m134): ds_read_b128 ~12cyc -> r5 gemm2 was LDS-BW bound (B re-read x4,
// q scalar reads). K2 here: 128-row blocks (halves LDS+L2 bytes/FLOP), r5-proven
// dbuf+barrier-per-agent mechanics, q transposed for b128 reads, hac in AGPRs.
//   convert: weights -> bf16 ws
//   K1 (r7 verbatim): gemm1 128rows x 640cols + wf/b1/v heads; h1 -> HBM pre-swizzled
//   K2: gemm2+mix: h1 tile LDS, w12b agent tiles dbuf-staged (once per block),
//       waves 4(row-quarter) x 2(e-half), 32 MFMA/wave/agent, 1 barrier/agent.

#define SDIM 512
#define HD   256
#define EDIM 64
#define NAG  32

typedef short short8v __attribute__((ext_vector_type(8)));
typedef short short4v __attribute__((ext_vector_type(4)));
typedef float f32x4  __attribute__((ext_vector_type(4)));

__device__ __forceinline__ unsigned short f2bf(float f) {
  unsigned int u = __float_as_uint(f);
  unsigned int r = (u + 0x7FFFu + ((u >> 16) & 1u)) >> 16;
  return (unsigned short)r;
}
__device__ __forceinline__ float bf2f(unsigned short u) {
  return __uint_as_float(((unsigned int)u) << 16);
}
__device__ __forceinline__ short4v cvt4(float4 a) {
  short4v r;
  r[0] = (short)f2bf(a.x); r[1] = (short)f2bf(a.y);
  r[2] = (short)f2bf(a.z); r[3] = (short)f2bf(a.w);
  return r;
}

// ---------------- convert weights to bf16 ----------------
__global__ void qmix_convert(const float* __restrict__ w1_0, const float* __restrict__ wf_0,
                             const float* __restrict__ hb_w, const float* __restrict__ v0_w,
                             const float* __restrict__ w1_2, const float* __restrict__ wf_2,
                             unsigned short* __restrict__ W0cat, unsigned short* __restrict__ w12b,
                             unsigned short* __restrict__ wf2b) {
  int i = blockIdx.x * 256 + threadIdx.x;
  if (i < 327680) {
    float v;
    if (i < 131072)      v = w1_0[i];
    else if (i < 262144) v = wf_0[i - 131072];
    else if (i < 294912) v = hb_w[i - 262144];
    else                 v = v0_w[i - 294912];
    W0cat[i] = f2bf(v);
  } else if (i < 851968) {
    w12b[i - 327680] = f2bf(w1_2[i - 327680]);
  } else if (i < 868352) {
    wf2b[i - 851968] = f2bf(wf_2[i - 851968]);
  }
}

// ---------------- K1: gemm1 + wf + heads, 128-row blocks (r7 verbatim) ----------------
__global__ __launch_bounds__(512, 2) void qmix_k1(
    const float* __restrict__ states, const unsigned short* __restrict__ W0cat,
    const unsigned short* __restrict__ wf2b,
    const float* __restrict__ b1_0, const float* __restrict__ bf_0,
    const float* __restrict__ hb_b, const float* __restrict__ v0_b,
    const float* __restrict__ v2_w, const float* __restrict__ bf_2,
    unsigned short* __restrict__ h1g, unsigned short* __restrict__ b1h,
    unsigned short* __restrict__ wfinh, float* __restrict__ vbuf)
{
  __shared__ unsigned short sA[128 * 512];     // 128 KB: states, then h1|hf (swizzled)

  const int t    = threadIdx.x;
  const int r0   = blockIdx.x * 128;
  const int wave = t >> 6, lane = t & 63;
  const int lrow = lane & 15, lk = lane >> 4;

  const int colbase = wave * 80;
  const unsigned short* bp[5];
#pragma unroll
  for (int f = 0; f < 5; f++)
    bp[f] = W0cat + (size_t)(colbase + f * 16 + lrow) * SDIM + 8 * lk;
  short8v bregs[2][5];
#pragma unroll
  for (int f = 0; f < 5; f++) bregs[0][f] = *(const short8v*)(bp[f]);
#pragma unroll
  for (int f = 0; f < 5; f++) bregs[1][f] = *(const short8v*)(bp[f] + 32);

  const float4* gS4 = (const float4*)(states + (size_t)r0 * SDIM);
  {
    float4 L[16];
#pragma unroll
    for (int h = 0; h < 2; h++) {
#pragma unroll
      for (int it = 0; it < 16; it++) L[it] = gS4[(h * 16 + it) * 512 + t];
#pragma unroll
      for (int it = 0; it < 16; it++) {
        int idx = (h * 16 + it) * 512 + t;
        int row = idx >> 7, c4 = idx & 127;
        int byte = row * 1024 + ((c4 * 8) ^ ((row & 7) << 4));
        *(short4v*)((char*)sA + byte) = cvt4(L[it]);
      }
    }
  }
  __syncthreads();   // bar1

  f32x4 acc[8][5];
#pragma unroll
  for (int i = 0; i < 8; i++)
#pragma unroll
    for (int f = 0; f < 5; f++) acc[i][f] = (f32x4){0.f, 0.f, 0.f, 0.f};

#pragma unroll 1
  for (int ks = 0; ks < 16; ks++) {
    const int p = ks & 1;
#pragma unroll
    for (int i = 0; i < 8; i++) {
      int row = i * 16 + lrow;
      int byte = row * 1024 + ((ks * 64 + lk * 16) ^ ((row & 7) << 4));
      short8v af = *(const short8v*)((const char*)sA + byte);
#pragma unroll
      for (int f = 0; f < 5; f++)
        acc[i][f] = __builtin_amdgcn_mfma_f32_16x16x32_bf16(af, bregs[p][f], acc[i][f], 0, 0, 0);
    }
    if (ks < 14) {
#pragma unroll
      for (int f = 0; f < 5; f++) bregs[p][f] = *(const short8v*)(bp[f] + (ks + 2) * 32);
    }
  }

  __syncthreads();   // bar2

  {
    float vs[8][4];
#pragma unroll
    for (int i = 0; i < 8; i++)
#pragma unroll
      for (int rr = 0; rr < 4; rr++) vs[i][rr] = 0.f;

#pragma unroll
    for (int f = 0; f < 5; f++) {
      int cb  = colbase + f * 16;
      int col = cb + lrow;
      if (cb < 512) {
        float bv = (cb < 256) ? b1_0[col] : bf_0[col - 256];
#pragma unroll
        for (int i = 0; i < 8; i++)
#pragma unroll
          for (int rr = 0; rr < 4; rr++) {
            int row = i * 16 + lk * 4 + rr;
            float v = fmaxf(acc[i][f][rr] + bv, 0.f);
            int byte = row * 1024 + ((col * 2) ^ ((row & 7) << 4));
            *(unsigned short*)((char*)sA + byte) = f2bf(v);
          }
      } else if (cb < 576) {
        int e = col - 512;
        float bv = hb_b[e];
#pragma unroll
        for (int i = 0; i < 8; i++)
#pragma unroll
          for (int rr = 0; rr < 4; rr++) {
            int row = i * 16 + lk * 4 + rr;
            b1h[(size_t)(r0 + row) * EDIM + e] = f2bf(acc[i][f][rr] + bv);
          }
      } else {
        int e = col - 576;
        float bv = v0_b[e], wv = v2_w[e];
#pragma unroll
        for (int i = 0; i < 8; i++)
#pragma unroll
          for (int rr = 0; rr < 4; rr++)
            vs[i][rr] = fmaf(fmaxf(acc[i][f][rr] + bv, 0.f), wv, vs[i][rr]);
      }
    }
    if (colbase == 560) {
#pragma unroll
      for (int i = 0; i < 8; i++)
#pragma unroll
        for (int rr = 0; rr < 4; rr++) {
          float v = vs[i][rr];
#pragma unroll
          for (int m = 1; m < 16; m <<= 1) v += __shfl_xor(v, m, 64);
          if (lrow == 0) vbuf[r0 + i * 16 + lk * 4 + rr] = v;
        }
    }
  }
  __syncthreads();   // bar3

  // wf head
  {
    const int wr2 = wave >> 1;
    const int wc2 = wave & 1;
    f32x4 wfa[2][2];
#pragma unroll
    for (int i2 = 0; i2 < 2; i2++)
#pragma unroll
      for (int j = 0; j < 2; j++) wfa[i2][j] = (f32x4){0.f, 0.f, 0.f, 0.f};
#pragma unroll
    for (int kf = 0; kf < 8; kf++) {
      short8v bf2v[2];
#pragma unroll
      for (int j = 0; j < 2; j++)
        bf2v[j] = *(const short8v*)(wf2b + (size_t)(wc2 * 32 + j * 16 + lrow) * HD + kf * 32 + 8 * lk);
#pragma unroll
      for (int i2 = 0; i2 < 2; i2++) {
        int row = wr2 * 32 + i2 * 16 + lrow;
        int byte = row * 1024 + 512 + ((kf * 64 + lk * 16) ^ ((row & 7) << 4));
        short8v af2 = *(const short8v*)((const char*)sA + byte);
#pragma unroll
        for (int j = 0; j < 2; j++)
          wfa[i2][j] = __builtin_amdgcn_mfma_f32_16x16x32_bf16(af2, bf2v[j], wfa[i2][j], 0, 0, 0);
      }
    }
#pragma unroll
    for (int i2 = 0; i2 < 2; i2++)
#pragma unroll
      for (int j = 0; j < 2; j++) {
        int e = wc2 * 32 + j * 16 + lrow;
#pragma unroll
        for (int r = 0; r < 4; r++) {
          int row = wr2 * 32 + i2 * 16 + lk * 4 + r;
          wfinh[(size_t)(r0 + row) * EDIM + e] = f2bf(fabsf(wfa[i2][j][r] + bf_2[e]));
        }
      }
  }

  // h1 repack to HBM (swizzle baked into layout)
  {
    char* dst = (char*)h1g + (size_t)r0 * 512;
#pragma unroll
    for (int u = 0; u < 8; u++) {
      int idx = u * 512 + t;
      int row = idx >> 5;
      int p   = (idx & 31) * 16;
      short8v v = *(const short8v*)((const char*)sA + row * 1024 + p);
      *(short8v*)(dst + row * 512 + p) = v;
    }
  }
}

// ---------------- K2: gemm2 + mix, 128-row blocks, LDS-dbuf agents ----------------
__global__ __launch_bounds__(512, 1) void qmix_k2(
    const unsigned short* __restrict__ h1g, const unsigned short* __restrict__ w12b,
    const float* __restrict__ agent_qs, const float* __restrict__ b1_2,
    const unsigned short* __restrict__ b1h, const unsigned short* __restrict__ wfinh,
    const float* __restrict__ vbuf, const float* __restrict__ v2_b,
    float* __restrict__ out)
{
  __shared__ unsigned char h1s[128 * 512];     // 64 KB (pre-swizzled bf16 [128][256])
  __shared__ unsigned short bbuf[2][16384];    // 64 KB agent-tile dbuf (swizzled)
  __shared__ float q_t[NAG * 136];             // 17.4 KB q^T [agent][row] (136: 16B-aligned rows)
  __shared__ float ypart[2][128];              // 1 KB

  const int t    = threadIdx.x;
  const int r0   = blockIdx.x * 128;
  const int wave = t >> 6, lane = t & 63;
  const int lrow = lane & 15, lk = lane >> 4;
  const int wr = wave >> 1;    // row-quarter 0..3 (32 rows each)
  const int wc = wave & 1;     // e-half

  // ---- phase 0: issue all staging loads, then write LDS, one barrier ----
  short8v Lh[8];
  {
    const char* src = (const char*)h1g + (size_t)r0 * 512;
#pragma unroll
    for (int it = 0; it < 8; it++)
      Lh[it] = *(const short8v*)(src + (it * 512 + t) * 16);
  }
  const float4* gq = (const float4*)(agent_qs + (size_t)r0 * NAG);
  float4 q0 = gq[t], q1 = gq[512 + t];
  short8v sreg[4];
#pragma unroll
  for (int rd = 0; rd < 4; rd++)
    sreg[rd] = *(const short8v*)(w12b + rd * 4096 + t * 8);   // agent 0

  {
#pragma unroll
    for (int it = 0; it < 8; it++)
      *(short8v*)(h1s + (it * 512 + t) * 16) = Lh[it];
    int row0 = t >> 3, a4 = (t & 7) * 4;
    q_t[(a4 + 0) * 136 + row0] = q0.x;
    q_t[(a4 + 1) * 136 + row0] = q0.y;
    q_t[(a4 + 2) * 136 + row0] = q0.z;
    q_t[(a4 + 3) * 136 + row0] = q0.w;
    int row1 = 64 + row0;
    q_t[(a4 + 0) * 136 + row1] = q1.x;
    q_t[(a4 + 1) * 136 + row1] = q1.y;
    q_t[(a4 + 2) * 136 + row1] = q1.z;
    q_t[(a4 + 3) * 136 + row1] = q1.w;
#pragma unroll
    for (int rd = 0; rd < 4; rd++) {
      int Lo = rd * 8192 + t * 16;
      *(short8v*)((char*)bbuf + (Lo ^ (((Lo >> 9) & 7) << 4))) = sreg[rd];
    }
  }
  __syncthreads();   // bar1: h1s, q_t, bbuf[0] ready

  // hoist A fragments (rows wr*32.., K=256): 16 short8v = 64 VGPR
  short8v afr[2][8];
#pragma unroll
  for (int i = 0; i < 2; i++) {
    int row = wr * 32 + i * 16 + lrow;
#pragma unroll
    for (int kf = 0; kf < 8; kf++)
      afr[i][kf] = *(const short8v*)(h1s + row * 512 + ((kf * 64 + lk * 16) ^ ((row & 7) << 4)));
  }

  f32x4 hac00 = (f32x4){0.f,0.f,0.f,0.f}, hac01 = (f32x4){0.f,0.f,0.f,0.f};
  f32x4 hac10 = (f32x4){0.f,0.f,0.f,0.f}, hac11 = (f32x4){0.f,0.f,0.f,0.f};

#pragma unroll 1
  for (int a = 0; a < NAG; a++) {
    if (a < NAG - 1) {
      const unsigned short* p = w12b + (size_t)(a + 1) * 16384;
#pragma unroll
      for (int rd = 0; rd < 4; rd++)
        sreg[rd] = *(const short8v*)(p + rd * 4096 + t * 8);
    }
    const char* rbase = (const char*)bbuf + (a & 1) * 32768;

    f32x4 T00 = (f32x4){0.f,0.f,0.f,0.f}, T01 = (f32x4){0.f,0.f,0.f,0.f};
    f32x4 T10 = (f32x4){0.f,0.f,0.f,0.f}, T11 = (f32x4){0.f,0.f,0.f,0.f};
    const int e0 = wc * 32 + lrow, e1 = e0 + 16;
#pragma unroll
    for (int kf = 0; kf < 8; kf++) {
      short8v b0 = *(const short8v*)(rbase + ((e0 * 512 + kf * 64 + lk * 16) ^ ((e0 & 7) << 4)));
      short8v b1v = *(const short8v*)(rbase + ((e1 * 512 + kf * 64 + lk * 16) ^ ((e1 & 7) << 4)));
      T00 = __builtin_amdgcn_mfma_f32_16x16x32_bf16(afr[0][kf], b0,  T00, 0, 0, 0);
      T10 = __builtin_amdgcn_mfma_f32_16x16x32_bf16(afr[1][kf], b0,  T10, 0, 0, 0);
      T01 = __builtin_amdgcn_mfma_f32_16x16x32_bf16(afr[0][kf], b1v, T01, 0, 0, 0);
      T11 = __builtin_amdgcn_mfma_f32_16x16x32_bf16(afr[1][kf], b1v, T11, 0, 0, 0);
    }
    float bb0 = b1_2[a * EDIM + e0];
    float bb1 = b1_2[a * EDIM + e1];
    float4 qa = *(const float4*)(&q_t[a * 136 + wr * 32 + lk * 4]);
    float4 qb = *(const float4*)(&q_t[a * 136 + wr * 32 + 16 + lk * 4]);
#pragma unroll
    for (int r = 0; r < 4; r++) {
      float qar = (r == 0) ? qa.x : (r == 1) ? qa.y : (r == 2) ? qa.z : qa.w;
      float qbr = (r == 0) ? qb.x : (r == 1) ? qb.y : (r == 2) ? qb.z : qb.w;
      hac00[r] = fmaf(qar, fabsf(T00[r] + bb0), hac00[r]);
      hac01[r] = fmaf(qar, fabsf(T01[r] + bb1), hac01[r]);
      hac10[r] = fmaf(qbr, fabsf(T10[r] + bb0), hac10[r]);
      hac11[r] = fmaf(qbr, fabsf(T11[r] + bb1), hac11[r]);
    }
    if (a < NAG - 1) {
      char* wb = (char*)bbuf + ((a & 1) ^ 1) * 32768;
#pragma unroll
      for (int rd = 0; rd < 4; rd++) {
        int Lo = rd * 8192 + t * 16;
        *(short8v*)(wb + (Lo ^ (((Lo >> 9) & 7) << 4))) = sreg[rd];
      }
    }
    __syncthreads();
  }

  // ---- epilogue: elu(hid + b1)*wfin, reduce over e ----
  {
    float ys0[4], ys1[4];
    const int e0 = wc * 32 + lrow, e1 = e0 + 16;
#pragma unroll
    for (int r = 0; r < 4; r++) {
      int row0 = wr * 32 + lk * 4 + r;
      int row1 = row0 + 16;
      size_t g0 = (size_t)(r0 + row0) * EDIM;
      size_t g1 = (size_t)(r0 + row1) * EDIM;
      float p00 = hac00[r] + bf2f(b1h[g0 + e0]);
      float p01 = hac01[r] + bf2f(b1h[g0 + e1]);
      float p10 = hac10[r] + bf2f(b1h[g1 + e0]);
      float p11 = hac11[r] + bf2f(b1h[g1 + e1]);
      float h00 = p00 > 0.f ? p00 : expm1f(p00);
      float h01 = p01 > 0.f ? p01 : expm1f(p01);
      float h10 = p10 > 0.f ? p10 : expm1f(p10);
      float h11 = p11 > 0.f ? p11 : expm1f(p11);
      ys0[r] = h00 * bf2f(wfinh[g0 + e0]) + h01 * bf2f(wfinh[g0 + e1]);
      ys1[r] = h10 * bf2f(wfinh[g1 + e0]) + h11 * bf2f(wfinh[g1 + e1]);
    }
#pragma unroll
    for (int m = 1; m < 16; m <<= 1)
#pragma unroll
      for (int r = 0; r < 4; r++) {
        ys0[r] += __shfl_xor(ys0[r], m, 64);
        ys1[r] += __shfl_xor(ys1[r], m, 64);
      }
    if (lrow == 0) {
#pragma unroll
      for (int r = 0; r < 4; r++) {
        ypart[wc][wr * 32 + lk * 4 + r]      = ys0[r];
        ypart[wc][wr * 32 + 16 + lk * 4 + r] = ys1[r];
      }
    }
  }
  __syncthreads();
  if (t < 128) {
    out[r0 + t] = ypart[0][t] + ypart[1][t] + vbuf[r0 + t] + v2_b[0];
  }
}

extern "C" void kernel_launch(void* const* d_in, const int* in_sizes, int n_in,
                              void* d_out, int out_size, void* d_ws, size_t ws_size,
                              hipStream_t stream) {
  const float* agent_qs = (const float*)d_in[0];
  const float* states   = (const float*)d_in[1];
  const float* w1_0 = (const float*)d_in[2];
  const float* b1_0 = (const float*)d_in[3];
  const float* w1_2 = (const float*)d_in[4];
  const float* b1_2 = (const float*)d_in[5];
  const float* wf_0 = (const float*)d_in[6];
  const float* bf_0 = (const float*)d_in[7];
  const float* wf_2 = (const float*)d_in[8];
  const float* bf_2 = (const float*)d_in[9];
  const float* hb_w = (const float*)d_in[10];
  const float* hb_b = (const float*)d_in[11];
  const float* v0_w = (const float*)d_in[12];
  const float* v0_b = (const float*)d_in[13];
  const float* v2_w = (const float*)d_in[14];
  const float* v2_b = (const float*)d_in[15];

  char* ws = (char*)d_ws;
  unsigned short* W0cat = (unsigned short*)ws;                  //    655,360 B
  unsigned short* w12b  = (unsigned short*)(ws + 655360);       //  1,048,576 B
  unsigned short* wf2b  = (unsigned short*)(ws + 1703936);      //     32,768 B
  unsigned short* h1g   = (unsigned short*)(ws + 1736704);      // 16,777,216 B
  unsigned short* b1h   = (unsigned short*)(ws + 18513920);     //  4,194,304 B
  unsigned short* wfinh = (unsigned short*)(ws + 22708224);     //  4,194,304 B
  float*          vbuf  = (float*)(ws + 26902528);              //    131,072 B

  qmix_convert<<<3392, 256, 0, stream>>>(w1_0, wf_0, hb_w, v0_w, w1_2, wf_2,
                                         W0cat, w12b, wf2b);
  qmix_k1<<<256, 512, 0, stream>>>(states, W0cat, wf2b, b1_0, bf_0, hb_b, v0_b,
                                   v2_w, bf_2, h1g, b1h, wfinh, vbuf);
  qmix_k2<<<256, 512, 0, stream>>>(h1g, w12b, agent_qs, b1_2, b1h, wfinh, vbuf,
                                   v2_b, (float*)d_out);
}

// Round 10
// 125.941 us; speedup vs baseline: 4.5822x; 1.0028x over previous
//
#include <hip/hip_runtime.h>

// QMixer — round 10: round 9 + ONE fix: K1 __launch_bounds__(512,1).
// r9 post-mortem: K1 WRITE_SIZE=147MB (ideal 24MB), VGPR=116 -> the (512,2)
// 128-VGPR cap spilled acc[8][5] (160 VGPRs) to scratch inside the k-loop.
// K1's 128KB LDS caps it at 1 block/CU anyway, so (512,1) is free occupancy-wise
// and lifts the VGPR cap to 256 (live set ~230, no spill). K2 unchanged (r9).

#define SDIM 512
#define HD   256
#define EDIM 64
#define NAG  32

typedef short short8v __attribute__((ext_vector_type(8)));
typedef short short4v __attribute__((ext_vector_type(4)));
typedef float f32x4  __attribute__((ext_vector_type(4)));

__device__ __forceinline__ unsigned short f2bf(float f) {
  unsigned int u = __float_as_uint(f);
  unsigned int r = (u + 0x7FFFu + ((u >> 16) & 1u)) >> 16;
  return (unsigned short)r;
}
__device__ __forceinline__ float bf2f(unsigned short u) {
  return __uint_as_float(((unsigned int)u) << 16);
}
__device__ __forceinline__ short4v cvt4(float4 a) {
  short4v r;
  r[0] = (short)f2bf(a.x); r[1] = (short)f2bf(a.y);
  r[2] = (short)f2bf(a.z); r[3] = (short)f2bf(a.w);
  return r;
}

// ---------------- convert weights to bf16 ----------------
__global__ void qmix_convert(const float* __restrict__ w1_0, const float* __restrict__ wf_0,
                             const float* __restrict__ hb_w, const float* __restrict__ v0_w,
                             const float* __restrict__ w1_2, const float* __restrict__ wf_2,
                             unsigned short* __restrict__ W0cat, unsigned short* __restrict__ w12b,
                             unsigned short* __restrict__ wf2b) {
  int i = blockIdx.x * 256 + threadIdx.x;
  if (i < 327680) {
    float v;
    if (i < 131072)      v = w1_0[i];
    else if (i < 262144) v = wf_0[i - 131072];
    else if (i < 294912) v = hb_w[i - 262144];
    else                 v = v0_w[i - 294912];
    W0cat[i] = f2bf(v);
  } else if (i < 851968) {
    w12b[i - 327680] = f2bf(w1_2[i - 327680]);
  } else if (i < 868352) {
    wf2b[i - 851968] = f2bf(wf_2[i - 851968]);
  }
}

// ---------------- K1: gemm1 + wf + heads, 128-row blocks ----------------
__global__ __launch_bounds__(512, 1) void qmix_k1(
    const float* __restrict__ states, const unsigned short* __restrict__ W0cat,
    const unsigned short* __restrict__ wf2b,
    const float* __restrict__ b1_0, const float* __restrict__ bf_0,
    const float* __restrict__ hb_b, const float* __restrict__ v0_b,
    const float* __restrict__ v2_w, const float* __restrict__ bf_2,
    unsigned short* __restrict__ h1g, unsigned short* __restrict__ b1h,
    unsigned short* __restrict__ wfinh, float* __restrict__ vbuf)
{
  __shared__ unsigned short sA[128 * 512];     // 128 KB: states, then h1|hf (swizzled)

  const int t    = threadIdx.x;
  const int r0   = blockIdx.x * 128;
  const int wave = t >> 6, lane = t & 63;
  const int lrow = lane & 15, lk = lane >> 4;

  const int colbase = wave * 80;
  const unsigned short* bp[5];
#pragma unroll
  for (int f = 0; f < 5; f++)
    bp[f] = W0cat + (size_t)(colbase + f * 16 + lrow) * SDIM + 8 * lk;
  short8v bregs[2][5];
#pragma unroll
  for (int f = 0; f < 5; f++) bregs[0][f] = *(const short8v*)(bp[f]);
#pragma unroll
  for (int f = 0; f < 5; f++) bregs[1][f] = *(const short8v*)(bp[f] + 32);

  const float4* gS4 = (const float4*)(states + (size_t)r0 * SDIM);
  {
    float4 L[16];
#pragma unroll
    for (int h = 0; h < 2; h++) {
#pragma unroll
      for (int it = 0; it < 16; it++) L[it] = gS4[(h * 16 + it) * 512 + t];
#pragma unroll
      for (int it = 0; it < 16; it++) {
        int idx = (h * 16 + it) * 512 + t;
        int row = idx >> 7, c4 = idx & 127;
        int byte = row * 1024 + ((c4 * 8) ^ ((row & 7) << 4));
        *(short4v*)((char*)sA + byte) = cvt4(L[it]);
      }
    }
  }
  __syncthreads();   // bar1

  f32x4 acc[8][5];
#pragma unroll
  for (int i = 0; i < 8; i++)
#pragma unroll
    for (int f = 0; f < 5; f++) acc[i][f] = (f32x4){0.f, 0.f, 0.f, 0.f};

#pragma unroll 1
  for (int ks = 0; ks < 16; ks++) {
    const int p = ks & 1;
#pragma unroll
    for (int i = 0; i < 8; i++) {
      int row = i * 16 + lrow;
      int byte = row * 1024 + ((ks * 64 + lk * 16) ^ ((row & 7) << 4));
      short8v af = *(const short8v*)((const char*)sA + byte);
#pragma unroll
      for (int f = 0; f < 5; f++)
        acc[i][f] = __builtin_amdgcn_mfma_f32_16x16x32_bf16(af, bregs[p][f], acc[i][f], 0, 0, 0);
    }
    if (ks < 14) {
#pragma unroll
      for (int f = 0; f < 5; f++) bregs[p][f] = *(const short8v*)(bp[f] + (ks + 2) * 32);
    }
  }

  __syncthreads();   // bar2

  {
    float vs[8][4];
#pragma unroll
    for (int i = 0; i < 8; i++)
#pragma unroll
      for (int rr = 0; rr < 4; rr++) vs[i][rr] = 0.f;

#pragma unroll
    for (int f = 0; f < 5; f++) {
      int cb  = colbase + f * 16;
      int col = cb + lrow;
      if (cb < 512) {
        float bv = (cb < 256) ? b1_0[col] : bf_0[col - 256];
#pragma unroll
        for (int i = 0; i < 8; i++)
#pragma unroll
          for (int rr = 0; rr < 4; rr++) {
            int row = i * 16 + lk * 4 + rr;
            float v = fmaxf(acc[i][f][rr] + bv, 0.f);
            int byte = row * 1024 + ((col * 2) ^ ((row & 7) << 4));
            *(unsigned short*)((char*)sA + byte) = f2bf(v);
          }
      } else if (cb < 576) {
        int e = col - 512;
        float bv = hb_b[e];
#pragma unroll
        for (int i = 0; i < 8; i++)
#pragma unroll
          for (int rr = 0; rr < 4; rr++) {
            int row = i * 16 + lk * 4 + rr;
            b1h[(size_t)(r0 + row) * EDIM + e] = f2bf(acc[i][f][rr] + bv);
          }
      } else {
        int e = col - 576;
        float bv = v0_b[e], wv = v2_w[e];
#pragma unroll
        for (int i = 0; i < 8; i++)
#pragma unroll
          for (int rr = 0; rr < 4; rr++)
            vs[i][rr] = fmaf(fmaxf(acc[i][f][rr] + bv, 0.f), wv, vs[i][rr]);
      }
    }
    if (colbase == 560) {
#pragma unroll
      for (int i = 0; i < 8; i++)
#pragma unroll
        for (int rr = 0; rr < 4; rr++) {
          float v = vs[i][rr];
#pragma unroll
          for (int m = 1; m < 16; m <<= 1) v += __shfl_xor(v, m, 64);
          if (lrow == 0) vbuf[r0 + i * 16 + lk * 4 + rr] = v;
        }
    }
  }
  __syncthreads();   // bar3

  // wf head
  {
    const int wr2 = wave >> 1;
    const int wc2 = wave & 1;
    f32x4 wfa[2][2];
#pragma unroll
    for (int i2 = 0; i2 < 2; i2++)
#pragma unroll
      for (int j = 0; j < 2; j++) wfa[i2][j] = (f32x4){0.f, 0.f, 0.f, 0.f};
#pragma unroll
    for (int kf = 0; kf < 8; kf++) {
      short8v bf2v[2];
#pragma unroll
      for (int j = 0; j < 2; j++)
        bf2v[j] = *(const short8v*)(wf2b + (size_t)(wc2 * 32 + j * 16 + lrow) * HD + kf * 32 + 8 * lk);
#pragma unroll
      for (int i2 = 0; i2 < 2; i2++) {
        int row = wr2 * 32 + i2 * 16 + lrow;
        int byte = row * 1024 + 512 + ((kf * 64 + lk * 16) ^ ((row & 7) << 4));
        short8v af2 = *(const short8v*)((const char*)sA + byte);
#pragma unroll
        for (int j = 0; j < 2; j++)
          wfa[i2][j] = __builtin_amdgcn_mfma_f32_16x16x32_bf16(af2, bf2v[j], wfa[i2][j], 0, 0, 0);
      }
    }
#pragma unroll
    for (int i2 = 0; i2 < 2; i2++)
#pragma unroll
      for (int j = 0; j < 2; j++) {
        int e = wc2 * 32 + j * 16 + lrow;
#pragma unroll
        for (int r = 0; r < 4; r++) {
          int row = wr2 * 32 + i2 * 16 + lk * 4 + r;
          wfinh[(size_t)(r0 + row) * EDIM + e] = f2bf(fabsf(wfa[i2][j][r] + bf_2[e]));
        }
      }
  }

  // h1 repack to HBM (swizzle baked into layout)
  {
    char* dst = (char*)h1g + (size_t)r0 * 512;
#pragma unroll
    for (int u = 0; u < 8; u++) {
      int idx = u * 512 + t;
      int row = idx >> 5;
      int p   = (idx & 31) * 16;
      short8v v = *(const short8v*)((const char*)sA + row * 1024 + p);
      *(short8v*)(dst + row * 512 + p) = v;
    }
  }
}

// ---------------- K2: gemm2 + mix, 128-row blocks, LDS-dbuf agents (r9 verbatim) ----------------
__global__ __launch_bounds__(512, 1) void qmix_k2(
    const unsigned short* __restrict__ h1g, const unsigned short* __restrict__ w12b,
    const float* __restrict__ agent_qs, const float* __restrict__ b1_2,
    const unsigned short* __restrict__ b1h, const unsigned short* __restrict__ wfinh,
    const float* __restrict__ vbuf, const float* __restrict__ v2_b,
    float* __restrict__ out)
{
  __shared__ unsigned char h1s[128 * 512];     // 64 KB (pre-swizzled bf16 [128][256])
  __shared__ unsigned short bbuf[2][16384];    // 64 KB agent-tile dbuf (swizzled)
  __shared__ float q_t[NAG * 136];             // 17.4 KB q^T [agent][row]
  __shared__ float ypart[2][128];              // 1 KB

  const int t    = threadIdx.x;
  const int r0   = blockIdx.x * 128;
  const int wave = t >> 6, lane = t & 63;
  const int lrow = lane & 15, lk = lane >> 4;
  const int wr = wave >> 1;    // row-quarter 0..3 (32 rows each)
  const int wc = wave & 1;     // e-half

  short8v Lh[8];
  {
    const char* src = (const char*)h1g + (size_t)r0 * 512;
#pragma unroll
    for (int it = 0; it < 8; it++)
      Lh[it] = *(const short8v*)(src + (it * 512 + t) * 16);
  }
  const float4* gq = (const float4*)(agent_qs + (size_t)r0 * NAG);
  float4 q0 = gq[t], q1 = gq[512 + t];
  short8v sreg[4];
#pragma unroll
  for (int rd = 0; rd < 4; rd++)
    sreg[rd] = *(const short8v*)(w12b + rd * 4096 + t * 8);   // agent 0

  {
#pragma unroll
    for (int it = 0; it < 8; it++)
      *(short8v*)(h1s + (it * 512 + t) * 16) = Lh[it];
    int row0 = t >> 3, a4 = (t & 7) * 4;
    q_t[(a4 + 0) * 136 + row0] = q0.x;
    q_t[(a4 + 1) * 136 + row0] = q0.y;
    q_t[(a4 + 2) * 136 + row0] = q0.z;
    q_t[(a4 + 3) * 136 + row0] = q0.w;
    int row1 = 64 + row0;
    q_t[(a4 + 0) * 136 + row1] = q1.x;
    q_t[(a4 + 1) * 136 + row1] = q1.y;
    q_t[(a4 + 2) * 136 + row1] = q1.z;
    q_t[(a4 + 3) * 136 + row1] = q1.w;
#pragma unroll
    for (int rd = 0; rd < 4; rd++) {
      int Lo = rd * 8192 + t * 16;
      *(short8v*)((char*)bbuf + (Lo ^ (((Lo >> 9) & 7) << 4))) = sreg[rd];
    }
  }
  __syncthreads();   // bar1

  short8v afr[2][8];
#pragma unroll
  for (int i = 0; i < 2; i++) {
    int row = wr * 32 + i * 16 + lrow;
#pragma unroll
    for (int kf = 0; kf < 8; kf++)
      afr[i][kf] = *(const short8v*)(h1s + row * 512 + ((kf * 64 + lk * 16) ^ ((row & 7) << 4)));
  }

  f32x4 hac00 = (f32x4){0.f,0.f,0.f,0.f}, hac01 = (f32x4){0.f,0.f,0.f,0.f};
  f32x4 hac10 = (f32x4){0.f,0.f,0.f,0.f}, hac11 = (f32x4){0.f,0.f,0.f,0.f};

#pragma unroll 1
  for (int a = 0; a < NAG; a++) {
    if (a < NAG - 1) {
      const unsigned short* p = w12b + (size_t)(a + 1) * 16384;
#pragma unroll
      for (int rd = 0; rd < 4; rd++)
        sreg[rd] = *(const short8v*)(p + rd * 4096 + t * 8);
    }
    const char* rbase = (const char*)bbuf + (a & 1) * 32768;

    f32x4 T00 = (f32x4){0.f,0.f,0.f,0.f}, T01 = (f32x4){0.f,0.f,0.f,0.f};
    f32x4 T10 = (f32x4){0.f,0.f,0.f,0.f}, T11 = (f32x4){0.f,0.f,0.f,0.f};
    const int e0 = wc * 32 + lrow, e1 = e0 + 16;
#pragma unroll
    for (int kf = 0; kf < 8; kf++) {
      short8v b0  = *(const short8v*)(rbase + ((e0 * 512 + kf * 64 + lk * 16) ^ ((e0 & 7) << 4)));
      short8v b1v = *(const short8v*)(rbase + ((e1 * 512 + kf * 64 + lk * 16) ^ ((e1 & 7) << 4)));
      T00 = __builtin_amdgcn_mfma_f32_16x16x32_bf16(afr[0][kf], b0,  T00, 0, 0, 0);
      T10 = __builtin_amdgcn_mfma_f32_16x16x32_bf16(afr[1][kf], b0,  T10, 0, 0, 0);
      T01 = __builtin_amdgcn_mfma_f32_16x16x32_bf16(afr[0][kf], b1v, T01, 0, 0, 0);
      T11 = __builtin_amdgcn_mfma_f32_16x16x32_bf16(afr[1][kf], b1v, T11, 0, 0, 0);
    }
    float bb0 = b1_2[a * EDIM + e0];
    float bb1 = b1_2[a * EDIM + e1];
    float4 qa = *(const float4*)(&q_t[a * 136 + wr * 32 + lk * 4]);
    float4 qb = *(const float4*)(&q_t[a * 136 + wr * 32 + 16 + lk * 4]);
#pragma unroll
    for (int r = 0; r < 4; r++) {
      float qar = (r == 0) ? qa.x : (r == 1) ? qa.y : (r == 2) ? qa.z : qa.w;
      float qbr = (r == 0) ? qb.x : (r == 1) ? qb.y : (r == 2) ? qb.z : qb.w;
      hac00[r] = fmaf(qar, fabsf(T00[r] + bb0), hac00[r]);
      hac01[r] = fmaf(qar, fabsf(T01[r] + bb1), hac01[r]);
      hac10[r] = fmaf(qbr, fabsf(T10[r] + bb0), hac10[r]);
      hac11[r] = fmaf(qbr, fabsf(T11[r] + bb1), hac11[r]);
    }
    if (a < NAG - 1) {
      char* wb = (char*)bbuf + ((a & 1) ^ 1) * 32768;
#pragma unroll
      for (int rd = 0; rd < 4; rd++) {
        int Lo = rd * 8192 + t * 16;
        *(short8v*)(wb + (Lo ^ (((Lo >> 9) & 7) << 4))) = sreg[rd];
      }
    }
    __syncthreads();
  }

  // epilogue
  {
    float ys0[4], ys1[4];
    const int e0 = wc * 32 + lrow, e1 = e0 + 16;
#pragma unroll
    for (int r = 0; r < 4; r++) {
      int row0 = wr * 32 + lk * 4 + r;
      int row1 = row0 + 16;
      size_t g0 = (size_t)(r0 + row0) * EDIM;
      size_t g1 = (size_t)(r0 + row1) * EDIM;
      float p00 = hac00[r] + bf2f(b1h[g0 + e0]);
      float p01 = hac01[r] + bf2f(b1h[g0 + e1]);
      float p10 = hac10[r] + bf2f(b1h[g1 + e0]);
      float p11 = hac11[r] + bf2f(b1h[g1 + e1]);
      float h00 = p00 > 0.f ? p00 : expm1f(p00);
      float h01 = p01 > 0.f ? p01 : expm1f(p01);
      float h10 = p10 > 0.f ? p10 : expm1f(p10);
      float h11 = p11 > 0.f ? p11 : expm1f(p11);
      ys0[r] = h00 * bf2f(wfinh[g0 + e0]) + h01 * bf2f(wfinh[g0 + e1]);
      ys1[r] = h10 * bf2f(wfinh[g1 + e0]) + h11 * bf2f(wfinh[g1 + e1]);
    }
#pragma unroll
    for (int m = 1; m < 16; m <<= 1)
#pragma unroll
      for (int r = 0; r < 4; r++) {
        ys0[r] += __shfl_xor(ys0[r], m, 64);
        ys1[r] += __shfl_xor(ys1[r], m, 64);
      }
    if (lrow == 0) {
#pragma unroll
      for (int r = 0; r < 4; r++) {
        ypart[wc][wr * 32 + lk * 4 + r]      = ys0[r];
        ypart[wc][wr * 32 + 16 + lk * 4 + r] = ys1[r];
      }
    }
  }
  __syncthreads();
  if (t < 128) {
    out[r0 + t] = ypart[0][t] + ypart[1][t] + vbuf[r0 + t] + v2_b[0];
  }
}

extern "C" void kernel_launch(void* const* d_in, const int* in_sizes, int n_in,
                              void* d_out, int out_size, void* d_ws, size_t ws_size,
                              hipStream_t stream) {
  const float* agent_qs = (const float*)d_in[0];
  const float* states   = (const float*)d_in[1];
  const float* w1_0 = (const float*)d_in[2];
  const float* b1_0 = (const float*)d_in[3];
  const float* w1_2 = (const float*)d_in[4];
  const float* b1_2 = (const float*)d_in[5];
  const float* wf_0 = (const float*)d_in[6];
  const float* bf_0 = (const float*)d_in[7];
  const float* wf_2 = (const float*)d_in[8];
  const float* bf_2 = (const float*)d_in[9];
  const float* hb_w = (const float*)d_in[10];
  const float* hb_b = (const float*)d_in[11];
  const float* v0_w = (const float*)d_in[12];
  const float* v0_b = (const float*)d_in[13];
  const float* v2_w = (const float*)d_in[14];
  const float* v2_b = (const float*)d_in[15];

  char* ws = (char*)d_ws;
  unsigned short* W0cat = (unsigned short*)ws;                  //    655,360 B
  unsigned short* w12b  = (unsigned short*)(ws + 655360);       //  1,048,576 B
  unsigned short* wf2b  = (unsigned short*)(ws + 1703936);      //     32,768 B
  unsigned short* h1g   = (unsigned short*)(ws + 1736704);      // 16,777,216 B
  unsigned short* b1h   = (unsigned short*)(ws + 18513920);     //  4,194,304 B
  unsigned short* wfinh = (unsigned short*)(ws + 22708224);     //  4,194,304 B
  float*          vbuf  = (float*)(ws + 26902528);              //    131,072 B

  qmix_convert<<<3392, 256, 0, stream>>>(w1_0, wf_0, hb_w, v0_w, w1_2, wf_2,
                                         W0cat, w12b, wf2b);
  qmix_k1<<<256, 512, 0, stream>>>(states, W0cat, wf2b, b1_0, bf_0, hb_b, v0_b,
                                   v2_w, bf_2, h1g, b1h, wfinh, vbuf);
  qmix_k2<<<256, 512, 0, stream>>>(h1g, w12b, agent_qs, b1_2, b1h, wfinh, vbuf,
                                   v2_b, (float*)d_out);
}